// Round 9
// baseline (479.862 us; speedup 1.0000x reference)
//
#include <hip/hip_runtime.h>
#include <hip/hip_bf16.h>

// Fused Conv3d(3->16,k=3,valid) + conv_b + ReLU + maxpool2x2x2
// + spatial mean(fp32) + /2 + bias + channel-sum  ->  out[32] fp32.
//
// R18 = R17 resubmit (Round-8 failure was "MI355X container failed twice"
// — broker/infra, kernel never executed; code audit found no OOB/hang).
//
// R17: BARRIER-FREE wave-private restructure (convoy breaker).
//  Evidence: R11/R13/R14/R16 all neutral; pipes (MFMA 29us, LDS ~40us,
//  VALU ~32us) SUM serially to the measured ~94us -> block-wide barriers
//  convoy all waves through the same phase; occupancy doesn't fix it.
//  Fix: block = 1 wave = (hp, 16-w tile, b); grid 63x8x32 = 16128 blocks.
//  Each wave stages its own 18 w-rows into PRIVATE LDS (4 slots x 1152 B,
//  pair-rotation), so producer==consumer: in-order per-wave DS replaces
//  ALL barriers (zero s_barrier in the kernel). 16+ independent waves/CU
//  drift out of phase -> MFMA/VALU/LDS/VMEM overlap.
//  - LDS cell [slot][row 0..17][hl 0..3] = 16B: [par0: ci0,ci1,ci2,0 |
//    par1: ...] bf16 (k = dl_rel*4+ci, dl_rel = 2*hs+par, hs picks pair
//    dp+hs = slot (dp+hs)&3). Bank swizzle phys = hl ^ (row&3): all 9
//    read taps and both write rounds verified uniform (8 lanes/group).
//  - Stage: round A (64 lanes: row=lane&15, hl=lane>>4), round B (8 lanes:
//    rows 16,17). 6 dword loads + 4 cvt_pk + 1 ds_write_b128 per lane.
//    wv==7 round B = zeros (w 128,129 don't exist; feed masked outputs).
//  - s_setprio(1) around MFMA cluster (T5: pays in independent-wave regime).
// (R12 core, verified absmax=0 x4): operand-swapped MFMA (M=spatial,
//  N=(ch,dd)), in-reg 2x2 pool + DPP dd-pool, pair rotation, ci-fast pack.
//  MFMA m32n32k16, D: col=lane&31, row=(reg&3)+8*(reg>>2)+4*(lane>>5).

typedef __attribute__((ext_vector_type(8)))  short  short8;
typedef __attribute__((ext_vector_type(16))) float  floatx16;

__device__ __forceinline__ short f2bf(float f) {
    unsigned u = __builtin_bit_cast(unsigned, f);
    unsigned r = (u + 0x7FFFu + ((u >> 16) & 1u)) >> 16;
    return (short)r;
}

__device__ __forceinline__ unsigned pkbf2(float a, float b) {
    __hip_bfloat162 h = __float22bfloat162_rn(float2{a, b});  // v_cvt_pk_bf16_f32
    unsigned r;
    __builtin_memcpy(&r, &h, 4);
    return r;
}

template <int CTRL>
__device__ __forceinline__ float dpp_max(float v) {
    int x = __builtin_bit_cast(int, v);
    int y = __builtin_amdgcn_mov_dpp(x, CTRL, 0xF, 0xF, true);
    return fmaxf(v, __builtin_bit_cast(float, y));
}

#define SLOTSZ 1152   // 18 rows x 64 B

// ---- init: wtab[f=kh*3+kw][lane][8] zero-padded B-frags + out = bias sums ----
__global__ void init_kernel(const float* __restrict__ wg,
                            const float* __restrict__ biasg,
                            short* __restrict__ wtab,   // d_ws: 9*64*8 bf16 = 9216 B
                            float* __restrict__ out)    // [32]
{
    const int t = threadIdx.x;               // 0..575
    if (t < 576) {
        const int lane = t & 63, f = t >> 6;
        const int kh = f / 3, kw = f % 3;
        const int m = lane & 31, hs = lane >> 5;
        const int ch = m >> 1, dd = m & 1;   // col = 2*ch + dd
        short8 v;
        #pragma unroll
        for (int j = 0; j < 8; ++j) {
            const int s = hs * 8 + j;        // k-slot: dl_rel = s>>2, ci = s&3
            const int dl = s >> 2, ci = s & 3;
            const int kd = dl - dd;
            v[j] = (ci < 3 && kd >= 0 && kd < 3)
                 ? f2bf(wg[ch * 81 + ci * 27 + kd * 9 + kh * 3 + kw]) : (short)0;
        }
        ((short8*)wtab)[f * 64 + lane] = v;
    }
    if (t < 32) {
        float s = 0.f;
        #pragma unroll
        for (int cc = 0; cc < 16; ++cc) s += biasg[cc];
        out[t] = s;   // conv blocks atomicAdd on top
    }
}

__global__ __launch_bounds__(64, 4) void fused_conv_pool_reduce(
    const float* __restrict__ xg,    // f32 [32][3][32][128][128]
    const short* __restrict__ wtab,  // bf16 frag table in d_ws
    const float* __restrict__ cbg,   // f32 [16]
    float* __restrict__ out)         // f32 [32]
{
    __shared__ __align__(16) short slots[4 * 18 * 32];  // 4,608 B private

    // XCD-aware bijective swizzle: 16128 = 8 XCDs x 2016.
    const int lin  = blockIdx.y * 63 + blockIdx.x;     // 0..16127
    const int nl   = (lin & 7) * 2016 + (lin >> 3);
    const int hp   = nl % 63;
    const int rest = nl / 63;      // 0..255
    const int wv   = rest & 7;
    const int b    = rest >> 3;
    const int wbase = wv * 16;

    const int lane = threadIdx.x;  // 0..63
    const int hs   = lane >> 5;

    // ---- resident B-frags (36 VGPR), conv-bias, validity masks ----
    short8 af[9];
    #pragma unroll
    for (int f = 0; f < 9; ++f) af[f] = ((const short8*)wtab)[f * 64 + lane];
    const float cbv = cbg[(lane >> 1) & 15];   // ch = (lane&31)>>1
    float maskA[4];
    #pragma unroll
    for (int a = 0; a < 4; ++a) {
        const bool ok = ((lane & 1) == 0) && (8 * wv + 2 * a + hs <= 62);
        maskA[a] = ok ? 1.0f : 0.0f;
    }

    // ---- stage maps ----
    // round A: 64 cells (row 0..15 x hl 0..3); w = wbase+row <= 127 always.
    const int rowA = lane & 15, hlA = lane >> 4;
    const int wadA = rowA * 64 + ((hlA ^ (rowA & 3)) * 16);
    const float* gA = xg + (size_t)b * 1572864 + (2 * hp + hlA) * 128 + wbase + rowA;
    // round B: 8 cells (rows 16,17 x hl 0..3) on lanes 0..7.
    const bool doB = (lane < 8);
    const bool wv7 = (wv == 7);               // rows 16,17 = w 128,129: zeros
    const int rowB = 16 + (lane & 1), hlB = (lane >> 1) & 3;
    const int wadB = rowB * 64 + ((hlB ^ (rowB & 3)) * 16);
    const float* gB = xg + (size_t)b * 1572864 + (2 * hp + hlB) * 128 + wbase + rowB;

    // ---- read map: row = wi+kw (0..17), hl = hh+kh, phys = hl ^ (row&3) ----
    const int wi = (lane >> 1) & 15, hh = lane & 1;
    int rad[3][3];
    #pragma unroll
    for (int kh = 0; kh < 3; ++kh) {
        #pragma unroll
        for (int kw = 0; kw < 3; ++kw) {
            const int row = wi + kw;
            rad[kh][kw] = row * 64 + (((hh + kh) ^ (row & 3)) * 16);
        }
    }

    // ---- pair load/write helpers (A: 6 dwords; B: 6 dwords on 8 lanes) ----
    float A0,A1,A2,A3,A4,A5, B0=0.f,B1=0.f,B2=0.f,B3=0.f,B4=0.f,B5=0.f;
    auto loadPair = [&](int p) {
        const float* pa = gA + (size_t)(2 * p) * 16384;
        A0 = pa[0];      A1 = pa[524288];  A2 = pa[1048576];   // par0: ci0,1,2
        A3 = pa[16384];  A4 = pa[540672];  A5 = pa[1064960];   // par1: ci0,1,2
        if (doB) {
            if (!wv7) {
                const float* pb = gB + (size_t)(2 * p) * 16384;
                B0 = pb[0];     B1 = pb[524288]; B2 = pb[1048576];
                B3 = pb[16384]; B4 = pb[540672]; B5 = pb[1064960];
            } else {
                B0 = B1 = B2 = B3 = B4 = B5 = 0.f;
            }
        }
    };
    auto writePair = [&](int sbase) {
        uint4 q;
        q.x = pkbf2(A0, A1);  q.y = pkbf2(A2, 0.f);
        q.z = pkbf2(A3, A4);  q.w = pkbf2(A5, 0.f);
        *(uint4*)((char*)slots + sbase + wadA) = q;       // ds_write_b128
        if (doB) {
            uint4 r;
            r.x = pkbf2(B0, B1);  r.y = pkbf2(B2, 0.f);
            r.z = pkbf2(B3, B4);  r.w = pkbf2(B5, 0.f);
            *(uint4*)((char*)slots + sbase + wadB) = r;
        }
    };

    // ---- prologue: pairs 0,1 resident; pair 2 prefetched ----
    loadPair(0); writePair(0);
    loadPair(1); writePair(SLOTSZ);
    loadPair(2);

    float vsum = 0.f;
    for (int dp = 0; dp < 15; ++dp) {
        if (dp <= 13) writePair(((dp + 2) & 3) * SLOTSZ);  // stage pair dp+2
        if (dp <= 12) loadPair(dp + 3);                    // prefetch pair dp+3

        // lane-half reads pair dp+hs from slot (dp+hs)&3 (in-order DS: no barrier)
        const int rbase = ((dp + hs) & 3) * SLOTSZ;

        floatx16 acc = {0.f,0.f,0.f,0.f,0.f,0.f,0.f,0.f,
                        0.f,0.f,0.f,0.f,0.f,0.f,0.f,0.f};
        __builtin_amdgcn_s_setprio(1);
        #pragma unroll
        for (int kh = 0; kh < 3; ++kh) {
            #pragma unroll
            for (int kw = 0; kw < 3; ++kw) {
                const short8 bf = *(const short8*)((char*)slots + rbase + rad[kh][kw]);
                acc = __builtin_amdgcn_mfma_f32_32x32x16_bf16(bf, af[kh * 3 + kw], acc, 0, 0, 0);
            }
        }
        __builtin_amdgcn_s_setprio(0);

        // epilogue: acc[4a..4a+3] = one 2x2 h/w window (in-reg max),
        // dd-pool = DPP ^1, then +cb, relu, masked accumulate.
        #pragma unroll
        for (int a = 0; a < 4; ++a) {
            float m01 = fmaxf(acc[4 * a],     acc[4 * a + 1]);
            float m23 = fmaxf(acc[4 * a + 2], acc[4 * a + 3]);
            float m   = fmaxf(m01, m23);
            m = dpp_max<0xB1>(m);                 // pool over dd (lane ^ 1)
            const float v = fmaxf(m + cbv, 0.f);  // +conv_b, relu (post-pool)
            vsum = fmaf(maskA[a], v, vsum);
        }
    }

    // mask already zeroed invalid lanes/groups: full-wave sum, one atomic
    float s = vsum;
    #pragma unroll
    for (int off = 1; off < 64; off <<= 1) s += __shfl_xor(s, off, 64);
    if (lane == 0) atomicAdd(&out[b], s * (1.0f / 119070.0f));  // /(15*63*63)/2
}

extern "C" void kernel_launch(void* const* d_in, const int* in_sizes, int n_in,
                              void* d_out, int out_size, void* d_ws, size_t ws_size,
                              hipStream_t stream) {
    const float* x      = (const float*)d_in[0];
    const float* conv_w = (const float*)d_in[1];
    const float* conv_b = (const float*)d_in[2];
    const float* bias   = (const float*)d_in[3];
    float* out = (float*)d_out;
    short* wtab = (short*)d_ws;   // 9216 B

    init_kernel<<<1, 576, 0, stream>>>(conv_w, bias, wtab, out);
    dim3 grid(63, 256);  // (hp, wv|b) pre-swizzle
    fused_conv_pool_reduce<<<grid, 64, 0, stream>>>(x, wtab, conv_b, out);
}

// Round 10
// 421.104 us; speedup vs baseline: 1.1395x; 1.1395x over previous
//
#include <hip/hip_runtime.h>
#include <hip/hip_bf16.h>

// Fused Conv3d(3->16,k=3,valid) + conv_b + ReLU + maxpool2x2x2
// + spatial mean(fp32) + /2 + bias + channel-sum  ->  out[32] fp32.
//
// R19: R18 (barrier-free 1-wave blocks, absmax=0) with the two perf wounds
// fixed — R18's 289us was spills + bank conflicts, NOT the design:
//  (a) SPILLS: launch_bounds(64,4) squeezed to 64 VGPR vs ~90 needed ->
//      301 MB scratch writes. Now launch_bounds(64,2) (cap 256) + reg diet.
//  (b) CONFLICTS (1.08e7): old row-major XOR swizzle gave only 4 distinct
//      16B-columns per read tap (16 lanes/column). New HL-MAJOR layout:
//      slot = [hl 0..3][row 0..17] x 16B (288 B per hl, 1152 B per slot).
//      Read tap addr = (hh+kh)*288 + (wi+kw)*16 = lane base + COMPILE-TIME
//      immediate -> rad[9] regs gone; columns (wi+2hh+c) mod 8 = exactly
//      8 lanes/column for all taps and both write rounds (uniform).
// Design (R17): block = 1 wave = (hp, 16-w tile, b); grid 63x8x32 = 16128.
//  Wave stages its own 18 w-rows into PRIVATE LDS (4 slots, pair rotation);
//  producer==consumer -> in-order per-wave DS, ZERO barriers. 16 WGs/CU
//  (1-wave WG cap) drift out of phase -> MFMA/VALU/LDS/VMEM overlap.
//  Cell 16B = [par0: ci0,ci1,ci2,0 | par1: ci0,ci1,ci2,0] bf16; lane-half
//  hs reads pair dp+hs from slot (dp+hs)&3 (dl_rel = 2hs+par).
//  Stage: round A (64 lanes: row=lane&15, hl=lane>>4), round B (8 lanes:
//  rows 16,17; wv==7 writes zeros - w 128,129 feed only masked outputs).
//  s_setprio(1) around MFMA cluster (T5, independent-wave regime).
// (R12 core, absmax=0 x5): operand-swapped MFMA (M=spatial, N=(ch,dd)),
//  in-reg 2x2 pool + DPP dd-pool, pair rotation, ci-fast pack.
//  MFMA m32n32k16, D: col=lane&31, row=(reg&3)+8*(reg>>2)+4*(lane>>5).

typedef __attribute__((ext_vector_type(8)))  short  short8;
typedef __attribute__((ext_vector_type(16))) float  floatx16;

__device__ __forceinline__ short f2bf(float f) {
    unsigned u = __builtin_bit_cast(unsigned, f);
    unsigned r = (u + 0x7FFFu + ((u >> 16) & 1u)) >> 16;
    return (short)r;
}

__device__ __forceinline__ unsigned pkbf2(float a, float b) {
    __hip_bfloat162 h = __float22bfloat162_rn(float2{a, b});  // v_cvt_pk_bf16_f32
    unsigned r;
    __builtin_memcpy(&r, &h, 4);
    return r;
}

template <int CTRL>
__device__ __forceinline__ float dpp_max(float v) {
    int x = __builtin_bit_cast(int, v);
    int y = __builtin_amdgcn_mov_dpp(x, CTRL, 0xF, 0xF, true);
    return fmaxf(v, __builtin_bit_cast(float, y));
}

#define SLOTSZ 1152   // [hl 0..3][row 0..17] x 16 B  (288 B per hl)

// ---- init: wtab[f=kh*3+kw][lane][8] zero-padded B-frags + out = bias sums ----
__global__ void init_kernel(const float* __restrict__ wg,
                            const float* __restrict__ biasg,
                            short* __restrict__ wtab,   // d_ws: 9*64*8 bf16 = 9216 B
                            float* __restrict__ out)    // [32]
{
    const int t = threadIdx.x;               // 0..575
    if (t < 576) {
        const int lane = t & 63, f = t >> 6;
        const int kh = f / 3, kw = f % 3;
        const int m = lane & 31, hs = lane >> 5;
        const int ch = m >> 1, dd = m & 1;   // col = 2*ch + dd
        short8 v;
        #pragma unroll
        for (int j = 0; j < 8; ++j) {
            const int s = hs * 8 + j;        // k-slot: dl_rel = s>>2, ci = s&3
            const int dl = s >> 2, ci = s & 3;
            const int kd = dl - dd;
            v[j] = (ci < 3 && kd >= 0 && kd < 3)
                 ? f2bf(wg[ch * 81 + ci * 27 + kd * 9 + kh * 3 + kw]) : (short)0;
        }
        ((short8*)wtab)[f * 64 + lane] = v;
    }
    if (t < 32) {
        float s = 0.f;
        #pragma unroll
        for (int cc = 0; cc < 16; ++cc) s += biasg[cc];
        out[t] = s;   // conv blocks atomicAdd on top
    }
}

__global__ __launch_bounds__(64, 2) void fused_conv_pool_reduce(
    const float* __restrict__ xg,    // f32 [32][3][32][128][128]
    const short* __restrict__ wtab,  // bf16 frag table in d_ws
    const float* __restrict__ cbg,   // f32 [16]
    float* __restrict__ out)         // f32 [32]
{
    __shared__ __align__(16) short slots[4 * 18 * 32];  // 4,608 B private

    // XCD-aware bijective swizzle: 16128 = 8 XCDs x 2016.
    const int lin  = blockIdx.y * 63 + blockIdx.x;     // 0..16127
    const int nl   = (lin & 7) * 2016 + (lin >> 3);
    const int hp   = nl % 63;
    const int rest = nl / 63;      // 0..255
    const int wv   = rest & 7;
    const int b    = rest >> 3;
    const int wbase = wv * 16;

    const int lane = threadIdx.x;  // 0..63
    const int hs   = lane >> 5;

    // ---- resident B-frags (36 VGPR), conv-bias, validity masks ----
    short8 af[9];
    #pragma unroll
    for (int f = 0; f < 9; ++f) af[f] = ((const short8*)wtab)[f * 64 + lane];
    const float cbv = cbg[(lane >> 1) & 15];   // ch = (lane&31)>>1
    float maskA[4];
    #pragma unroll
    for (int a = 0; a < 4; ++a) {
        const bool ok = ((lane & 1) == 0) && (8 * wv + 2 * a + hs <= 62);
        maskA[a] = ok ? 1.0f : 0.0f;
    }

    // ---- stage maps (hl-major: addr = hl*288 + row*16) ----
    // round A: 64 cells (row 0..15 x hl 0..3); w = wbase+row <= 127 always.
    const int rowA = lane & 15, hlA = lane >> 4;
    const int wadA = hlA * 288 + rowA * 16;
    const float* gA = xg + (size_t)b * 1572864 + (2 * hp + hlA) * 128 + wbase + rowA;
    // round B: 8 cells (rows 16,17 x hl 0..3) on lanes 0..7.
    const bool doB = (lane < 8);
    const bool wv7 = (wv == 7);               // rows 16,17 = w 128,129: zeros
    const int rowB = 16 + (lane & 1), hlB = (lane >> 1) & 3;
    const int wadB = hlB * 288 + rowB * 16;
    const float* gB = xg + (size_t)b * 1572864 + (2 * hp + hlB) * 128 + wbase + rowB;

    // ---- read base: lane (wi,hh); tap offset = kh*288 + kw*16 (imm) ----
    const int wi = (lane >> 1) & 15, hh = lane & 1;
    const int rbase0 = hh * 288 + wi * 16;

    // ---- pair load/write helpers (A: 6 dwords; B: 6 dwords on 8 lanes) ----
    float A0,A1,A2,A3,A4,A5, B0=0.f,B1=0.f,B2=0.f,B3=0.f,B4=0.f,B5=0.f;
    auto loadPair = [&](int p) {
        const float* pa = gA + (size_t)(2 * p) * 16384;
        A0 = pa[0];      A1 = pa[524288];  A2 = pa[1048576];   // par0: ci0,1,2
        A3 = pa[16384];  A4 = pa[540672];  A5 = pa[1064960];   // par1: ci0,1,2
        if (doB) {
            if (!wv7) {
                const float* pb = gB + (size_t)(2 * p) * 16384;
                B0 = pb[0];     B1 = pb[524288]; B2 = pb[1048576];
                B3 = pb[16384]; B4 = pb[540672]; B5 = pb[1064960];
            } else {
                B0 = B1 = B2 = B3 = B4 = B5 = 0.f;
            }
        }
    };
    auto writePair = [&](int sbase) {
        uint4 q;
        q.x = pkbf2(A0, A1);  q.y = pkbf2(A2, 0.f);
        q.z = pkbf2(A3, A4);  q.w = pkbf2(A5, 0.f);
        *(uint4*)((char*)slots + sbase + wadA) = q;       // ds_write_b128
        if (doB) {
            uint4 r;
            r.x = pkbf2(B0, B1);  r.y = pkbf2(B2, 0.f);
            r.z = pkbf2(B3, B4);  r.w = pkbf2(B5, 0.f);
            *(uint4*)((char*)slots + sbase + wadB) = r;
        }
    };

    // ---- prologue: pairs 0,1 resident; pair 2 prefetched ----
    loadPair(0); writePair(0);
    loadPair(1); writePair(SLOTSZ);
    loadPair(2);

    float vsum = 0.f;
    for (int dp = 0; dp < 15; ++dp) {
        if (dp <= 13) writePair(((dp + 2) & 3) * SLOTSZ);  // stage pair dp+2
        if (dp <= 12) loadPair(dp + 3);                    // prefetch pair dp+3

        // lane-half reads pair dp+hs from slot (dp+hs)&3 (in-order DS: no barrier)
        const int rb = ((dp + hs) & 3) * SLOTSZ + rbase0;

        floatx16 acc = {0.f,0.f,0.f,0.f,0.f,0.f,0.f,0.f,
                        0.f,0.f,0.f,0.f,0.f,0.f,0.f,0.f};
        __builtin_amdgcn_s_setprio(1);
        #pragma unroll
        for (int kh = 0; kh < 3; ++kh) {
            #pragma unroll
            for (int kw = 0; kw < 3; ++kw) {
                const short8 bf = *(const short8*)((char*)slots + rb + (kh * 288 + kw * 16));
                acc = __builtin_amdgcn_mfma_f32_32x32x16_bf16(bf, af[kh * 3 + kw], acc, 0, 0, 0);
            }
        }
        __builtin_amdgcn_s_setprio(0);

        // epilogue: acc[4a..4a+3] = one 2x2 h/w window (in-reg max),
        // dd-pool = DPP ^1, then +cb, relu, masked accumulate.
        #pragma unroll
        for (int a = 0; a < 4; ++a) {
            float m01 = fmaxf(acc[4 * a],     acc[4 * a + 1]);
            float m23 = fmaxf(acc[4 * a + 2], acc[4 * a + 3]);
            float m   = fmaxf(m01, m23);
            m = dpp_max<0xB1>(m);                 // pool over dd (lane ^ 1)
            const float v = fmaxf(m + cbv, 0.f);  // +conv_b, relu (post-pool)
            vsum = fmaf(maskA[a], v, vsum);
        }
    }

    // mask already zeroed invalid lanes/groups: full-wave sum, one atomic
    float s = vsum;
    #pragma unroll
    for (int off = 1; off < 64; off <<= 1) s += __shfl_xor(s, off, 64);
    if (lane == 0) atomicAdd(&out[b], s * (1.0f / 119070.0f));  // /(15*63*63)/2
}

extern "C" void kernel_launch(void* const* d_in, const int* in_sizes, int n_in,
                              void* d_out, int out_size, void* d_ws, size_t ws_size,
                              hipStream_t stream) {
    const float* x      = (const float*)d_in[0];
    const float* conv_w = (const float*)d_in[1];
    const float* conv_b = (const float*)d_in[2];
    const float* bias   = (const float*)d_in[3];
    float* out = (float*)d_out;
    short* wtab = (short*)d_ws;   // 9216 B

    init_kernel<<<1, 576, 0, stream>>>(conv_w, bias, wtab, out);
    dim3 grid(63, 256);  // (hp, wv|b) pre-swizzle
    fused_conv_pool_reduce<<<grid, 64, 0, stream>>>(x, wtab, conv_b, out);
}

// Round 11
// 288.736 us; speedup vs baseline: 1.6619x; 1.4584x over previous
//
#include <hip/hip_runtime.h>
#include <hip/hip_bf16.h>

// Fused Conv3d(3->16,k=3,valid) + conv_b + ReLU + maxpool2x2x2
// + spatial mean(fp32) + /2 + bias + channel-sum  ->  out[32] fp32.
//
// R20: REVERT to R12 (best verified: 285.7us, absmax=0). Rounds 13-19
// probed every structural lever around this design and all were neutral
// or negative:
//   R11 latency depth-2 + no-vmcnt barrier: null (not latency-bound)
//   R13 LDS-read cut via DPP exchange:      -2us (VALU slots pricier)
//   R14 6-slot rotation, half the barriers: -3us
//   R16 4x 256-thr blocks (2x barrier grps): null (overlap didn't emerge)
//   R17-19 barrier-free 1-wave blocks:      -50..-150us (1-wave WGs cap at
//       ~7 waves/CU -> latency-exposed; spills/conflicts en route)
// Conclusion: conv ~93us = serial pipe sum (LDS ~44 + VALU ~32 + MFMA ~29)
// at a scheduling equilibrium; only raw work-cuts (R10, R12) ever paid.
//
// R12 design: issue-rate diet.
//  - OPERAND SWAP: acc = mfma(spatial, weights) -> M=(wi,hh) spatial rows in
//    regs, N=(ch,dd) cols on lanes (col=2ch+dd). Each lane's acc[4a..4a+3] is
//    one full 2x2 h/w pool window -> pooled IN-REGISTER (3 v_max); dd-pool is
//    one DPP(^1); +conv_b+relu once per POOLED value (monotone).
//  - D-PLANE ROTATION: LDS k-slots keyed by ABSOLUTE dl = d&3. Per iter stage
//    only the 2 NEW planes (pair dp+2) into the buffer freed 2 iters ago.
//    Odd-dp slot rotation (^8 slots) = addr^16; buffer select = ((dp+hs)>>1)&1.
//  - ci-fast slots, XOR bank swizzle, lgkm-only BAR (no vmcnt drain),
//    XCD-aware bijective block swizzle, 1 barrier/iter.
//  MFMA m32n32k16, D: col=lane&31, row=(reg&3)+8*(reg>>2)+4*(lane>>5).

typedef __attribute__((ext_vector_type(8)))  short  short8;
typedef __attribute__((ext_vector_type(2)))  float  floatx2;
typedef __attribute__((ext_vector_type(4)))  float  floatx4;
typedef __attribute__((ext_vector_type(16))) float  floatx16;

__device__ __forceinline__ short f2bf(float f) {
    unsigned u = __builtin_bit_cast(unsigned, f);
    unsigned r = (u + 0x7FFFu + ((u >> 16) & 1u)) >> 16;
    return (short)r;
}

__device__ __forceinline__ unsigned pkbf2(float a, float b) {
    __hip_bfloat162 h = __float22bfloat162_rn(float2{a, b});  // v_cvt_pk_bf16_f32
    unsigned r;
    __builtin_memcpy(&r, &h, 4);
    return r;
}

template <int CTRL>
__device__ __forceinline__ float dpp_max(float v) {
    int x = __builtin_bit_cast(int, v);
    int y = __builtin_amdgcn_mov_dpp(x, CTRL, 0xF, 0xF, true);
    return fmaxf(v, __builtin_bit_cast(float, y));
}

// LDS-only barrier: drain DS ops, leave global loads in flight (no vmcnt).
#define BAR() asm volatile("s_waitcnt lgkmcnt(0)\n\ts_barrier" ::: "memory")

#define BUFSZ 16640

// ---- init: wtab[f=kh*3+kw][lane][8] zero-padded B-frags + out = bias sums ----
// B operand: col n = lane&31 = 2*ch + dd; k-slot rel = (lane>>5)*8+j,
// dl_rel = slot>>2, ci = slot&3 (ci-fast); kd = dl_rel - dd.
__global__ void init_kernel(const float* __restrict__ wg,
                            const float* __restrict__ biasg,
                            short* __restrict__ wtab,   // d_ws: 9*64*8 bf16 = 9216 B
                            float* __restrict__ out)    // [32]
{
    const int t = threadIdx.x;               // 0..575
    if (t < 576) {
        const int lane = t & 63, f = t >> 6;
        const int kh = f / 3, kw = f % 3;
        const int m = lane & 31, hs = lane >> 5;
        const int ch = m >> 1, dd = m & 1;   // col = 2*ch + dd
        short8 v;
        #pragma unroll
        for (int j = 0; j < 8; ++j) {
            const int s = hs * 8 + j;        // k-slot: dl_rel = s>>2, ci = s&3
            const int dl = s >> 2, ci = s & 3;
            const int kd = dl - dd;
            v[j] = (ci < 3 && kd >= 0 && kd < 3)
                 ? f2bf(wg[ch * 81 + ci * 27 + kd * 9 + kh * 3 + kw]) : (short)0;
        }
        ((short8*)wtab)[f * 64 + lane] = v;
    }
    if (t < 32) {
        float s = 0.f;
        #pragma unroll
        for (int cc = 0; cc < 16; ++cc) s += biasg[cc];
        out[t] = s;   // conv blocks atomicAdd on top
    }
}

__global__ __launch_bounds__(512, 4) void fused_conv_pool_reduce(
    const float* __restrict__ xg,    // f32 [32][3][32][128][128]
    const short* __restrict__ wtab,  // bf16 frag table in d_ws
    const float* __restrict__ cbg,   // f32 [16]
    float* __restrict__ out)         // f32 [32]
{
    __shared__ __align__(16) short rawT[2 * 130 * 64];  // 33,280 B (2 buffers)
    __shared__ float wsums[8];

    // XCD-aware bijective swizzle: 2016 = 8 XCDs x 252 (4 b x 63 hp each).
    const int lin = blockIdx.y * 63 + blockIdx.x;      // 0..2015
    const int nl  = (lin & 7) * 252 + (lin >> 3);
    const int hp  = nl % 63;
    const int b   = nl / 63;

    const int tid = threadIdx.x;  // 0..511
    const int lane = tid & 63;
    const int wv   = tid >> 6;    // wave = 16-wide w tile
    const int hs   = lane >> 5;

    // ---- resident B-frags (36 VGPR), conv-bias, validity masks ----
    short8 af[9];
    #pragma unroll
    for (int f = 0; f < 9; ++f) af[f] = ((const short8*)wtab)[f * 64 + lane];
    const float cbv = cbg[(lane >> 1) & 15];   // ch = (lane&31)>>1
    float maskA[4];
    #pragma unroll
    for (int a = 0; a < 4; ++a) {
        const bool ok = ((lane & 1) == 0) && (wv * 8 + 2 * a + hs <= 62);
        maskA[a] = ok ? 1.0f : 0.0f;
    }

    // ---- zero rows 128/129 of both buffers (once) ----
    if (tid < 64)
        *(unsigned long long*)((char*)rawT + (tid >> 5) * BUFSZ + 16384 + (tid & 31) * 8) = 0ULL;

    #define SWZ(r) (((r) ^ ((r) >> 3)) & 7)

    // ---- per-iter stage map: 2 planes (pair dp+2), 2 rows x 8B per thread ----
    const int w4 = tid & 31, dr2 = (tid >> 5) & 1, rr = (tid >> 6) & 1, hr2 = (tid >> 7) & 3;
    int waddr2[2];
    #pragma unroll
    for (int j = 0; j < 2; ++j) {
        const int row = 2 * w4 + 64 * rr + j;
        waddr2[j] = row * 128 + ((hr2 * 2) ^ SWZ(row)) * 16 + dr2 * 8;  // ^ (p<<4) at runtime
    }

    // ---- read map (A = spatial): row = wv*16 + wi + kw, chunk = (hh+kh)*2 + hs ----
    const int wi = (lane >> 1) & 15, hh = lane & 1;
    int raddr[3][3];
    #pragma unroll
    for (int kh = 0; kh < 3; ++kh) {
        #pragma unroll
        for (int kw = 0; kw < 3; ++kw) {
            const int row = wv * 16 + wi + kw;
            const int phys = ((hh + kh) * 2 + hs) ^ SWZ(row);
            raddr[kh][kw] = row * 128 + phys * 16;   // ^ (p<<4) + rbuf*BUFSZ at runtime
        }
    }

    // ---- prologue: stage pairs 0,1 (planes 0..3) into buffer 0 ----
    {
        const int w4p = tid & 31, drp = (tid >> 5) & 3, hrp = (tid >> 7) & 3;
        const float* srcP = xg + ((size_t)b * 96 + drp) * 16384 + (2 * hp + hrp) * 128 + 4 * w4p;
        const floatx4 c0 = *(const floatx4*)(srcP);
        const floatx4 c1 = *(const floatx4*)(srcP + 524288);
        const floatx4 c2 = *(const floatx4*)(srcP + 1048576);
        const int chunkL = hrp * 2 + (drp >> 1);
        #pragma unroll
        for (int i = 0; i < 4; ++i) {
            const int row = 4 * w4p + i;
            const int ad = row * 128 + (chunkL ^ SWZ(row)) * 16 + (drp & 1) * 8;
            uint2 pk;
            pk.x = pkbf2(c0[i], c1[i]);
            pk.y = pkbf2(c2[i], 0.0f);
            *(uint2*)((char*)rawT + ad) = pk;
        }
    }

    // ---- prologue prefetch: pair 2 (planes 4,5), float2 per ci ----
    const float* src2 = xg + ((size_t)b * 96 + 4 + dr2) * 16384
                      + (2 * hp + hr2) * 128 + 2 * w4 + 64 * rr;
    floatx2 A0 = *(const floatx2*)(src2);
    floatx2 A1 = *(const floatx2*)(src2 + 524288);
    floatx2 A2 = *(const floatx2*)(src2 + 1048576);

    float vsum = 0.f;
    for (int dp = 0; dp < 15; ++dp) {
        const int p16 = (dp & 1) << 4;
        if (dp <= 13) {
            // stage pair dp+2 into buffer ((dp>>1)+1)&1, chunk-group = dp&1
            const int bw = (((dp >> 1) + 1) & 1) * BUFSZ;
            uint2 pk0, pk1;
            pk0.x = pkbf2(A0[0], A1[0]); pk0.y = pkbf2(A2[0], 0.0f);
            pk1.x = pkbf2(A0[1], A1[1]); pk1.y = pkbf2(A2[1], 0.0f);
            *(uint2*)((char*)rawT + bw + (waddr2[0] ^ p16)) = pk0;
            *(uint2*)((char*)rawT + bw + (waddr2[1] ^ p16)) = pk1;
            if (dp <= 12) {     // prefetch pair dp+3 (full-iter latency cover)
                src2 += 32768;
                A0 = *(const floatx2*)(src2);
                A1 = *(const floatx2*)(src2 + 524288);
                A2 = *(const floatx2*)(src2 + 1048576);
            }
        }
        BAR();   // LDS-only; global loads stay in flight

        // read buffer per lane-half: pair (dp+hs) -> buffer ((dp+hs)>>1)&1
        const int roff = (((dp + hs) >> 1) & 1) * BUFSZ;

        floatx16 acc = {0.f,0.f,0.f,0.f,0.f,0.f,0.f,0.f,
                        0.f,0.f,0.f,0.f,0.f,0.f,0.f,0.f};
        #pragma unroll
        for (int kh = 0; kh < 3; ++kh) {
            #pragma unroll
            for (int kw = 0; kw < 3; ++kw) {
                const short8 bf = *(const short8*)((char*)rawT + roff + (raddr[kh][kw] ^ p16));
                acc = __builtin_amdgcn_mfma_f32_32x32x16_bf16(bf, af[kh * 3 + kw], acc, 0, 0, 0);
            }
        }
        // epilogue: acc[4a..4a+3] = one 2x2 h/w window (in-reg max),
        // dd-pool = DPP ^1, then +cb, relu, masked accumulate.
        #pragma unroll
        for (int a = 0; a < 4; ++a) {
            float m01 = fmaxf(acc[4 * a],     acc[4 * a + 1]);
            float m23 = fmaxf(acc[4 * a + 2], acc[4 * a + 3]);
            float m   = fmaxf(m01, m23);
            m = dpp_max<0xB1>(m);                 // pool over dd (lane ^ 1)
            const float v = fmaxf(m + cbv, 0.f);  // +conv_b, relu (post-pool)
            vsum = fmaf(maskA[a], v, vsum);
        }
    }

    // mask already zeroes invalid lanes/groups: plain full-wave sum
    float s = vsum;
    #pragma unroll
    for (int off = 1; off < 64; off <<= 1) s += __shfl_xor(s, off, 64);

    if (lane == 0) wsums[wv] = s;
    __syncthreads();
    if (tid == 0) {
        float bs = 0.f;
        #pragma unroll
        for (int i = 0; i < 8; ++i) bs += wsums[i];
        atomicAdd(&out[b], bs * (1.0f / 119070.0f));   // /(15*63*63)/2
    }
}

extern "C" void kernel_launch(void* const* d_in, const int* in_sizes, int n_in,
                              void* d_out, int out_size, void* d_ws, size_t ws_size,
                              hipStream_t stream) {
    const float* x      = (const float*)d_in[0];
    const float* conv_w = (const float*)d_in[1];
    const float* conv_b = (const float*)d_in[2];
    const float* bias   = (const float*)d_in[3];
    float* out = (float*)d_out;
    short* wtab = (short*)d_ws;   // 9216 B

    init_kernel<<<1, 576, 0, stream>>>(conv_w, bias, wtab, out);
    dim3 grid(63, 32);  // (hp, b) pre-swizzle
    fused_conv_pool_reduce<<<grid, 512, 0, stream>>>(x, wtab, conv_b, out);
}